// Round 13
// baseline (925.545 us; speedup 1.0000x reference)
//
#include <hip/hip_runtime.h>
#include <hip/hip_cooperative_groups.h>
#include <math.h>

namespace cg = cooperative_groups;

// Problem constants (from setup_inputs): N=8, H=768, W=360, D=512
#define N_IMG 8
#define H 768
#define W 360
#define D 512
#define SY 383.5f         // (H-1)/2
#define SC 0.00436332312998582394f  // pi/(2W) = pi/720
#define NC 24             // 768/32 m-chunks
#define IPAD 384          // i dimension padded 360 -> 384
#define KSTEPS 10         // 10 x 32 = K 320 band
#define SMEM_BYTES 16640  // max over phases (phase1: 2 x 32 x 65 floats)

typedef __fp16 h2 __attribute__((ext_vector_type(2)));
struct H2X2 { h2 a, b; };        // 8B LDS entry: {img01@y, img23@y}
typedef short short8 __attribute__((ext_vector_type(8)));   // 8 bf16 (4 VGPRs)
typedef float f32x4 __attribute__((ext_vector_type(4)));

// fp32 -> bf16 pair, round-to-nearest-even, packed into one uint
__device__ inline unsigned bf16pair(float a, float b) {
    unsigned ua = __builtin_bit_cast(unsigned, a);
    unsigned ub = __builtin_bit_cast(unsigned, b);
    ua += 0x7FFFu + ((ua >> 16) & 1u);
    ub += 0x7FFFu + ((ub >> 16) & 1u);
    return (ua >> 16) | (ub & 0xFFFF0000u);
}

// ---------------------------------------------------------------------------
// Phase 0: g[m] = (1/H) sum_k hG[k] cos(2*pi*k*m/H)  (blocks 0..767, block
// reduction over 512 threads covering 768 k-terms) + zero the atomic output
// (all 1024 blocks x 512 thr x 1 float4 = exactly 8 MB).
// ---------------------------------------------------------------------------
__device__ void phase0_g_zero(int bid, int tid, const float* __restrict__ hG,
                              float* __restrict__ g, float4* __restrict__ out4,
                              void* smem) {
    out4[bid * 512 + tid] = make_float4(0.f, 0.f, 0.f, 0.f);
    if (bid < H) {
        float* lred = (float*)smem;    // 8 floats
        int m = bid;
        int p0 = (tid * m) % H;
        float s = hG[tid] * cosf((float)p0 * 0.00818123086872313911f);  // 2pi/768
        if (tid < 256) {
            int k = tid + 512;
            int p1 = (k * m) % H;
            s += hG[k] * cosf((float)p1 * 0.00818123086872313911f);
        }
#pragma unroll
        for (int off = 32; off > 0; off >>= 1) s += __shfl_down(s, off);
        if ((tid & 63) == 0) lred[tid >> 6] = s;
        __syncthreads();
        if (tid == 0) {
            float t = 0.f;
#pragma unroll
            for (int w2 = 0; w2 < 8; ++w2) t += lred[w2];
            g[m] = t * (1.0f / (float)H);
        }
    }
}

// ---------------------------------------------------------------------------
// Phase 1a (blocks 0..575): A-matrix transpose + bf16 pack.
// px == i exactly -> rc[n][i][m] = radon[n][m][i]. 2 256-thread tile-units
// per block; coalesced float4 loads -> LDS (pad 65) -> transposed bf16x8
// pack -> contiguous uint4 store. 1152 tiles total.
// ---------------------------------------------------------------------------
__device__ void phase1_rc(int bid, int tid, const float* __restrict__ radon,
                          uint4* __restrict__ rcC, void* smem) {
    typedef float XS[32][65];
    XS* xs2 = (XS*)smem;               // 2 x 8.3 KB
    const int unit = tid >> 8;         // 0/1
    const int sub  = tid & 255;
    const int tv = bid * 2 + unit;     // 0..1151
    float (*xs)[65] = xs2[unit];

    const int i0 = (tv % 6) * 64;
    const int c  = (tv / 6) % NC;
    const int n  = tv / 144;

    {
        int mr    = sub >> 3;          // 0..31
        int lane8 = sub & 7;
        int ib = i0 + lane8 * 8;
        const float* src = radon + ((size_t)n * H + 32 * c + mr) * W + ib;
        float4 v0 = make_float4(0.f, 0.f, 0.f, 0.f), v1 = v0;
        if (ib + 7 < W) {              // 360 % 8 == 0: all-valid or all-invalid
            v0 = *(const float4*)src;
            v1 = *(const float4*)(src + 4);
        }
        *(float4*)&xs[mr][lane8 * 8]     = v0;
        *(float4*)&xs[mr][lane8 * 8 + 4] = v1;
    }
    __syncthreads();

    const int il  = sub >> 2;          // 0..63
    const int oct = sub & 3;
    float v[8];
#pragma unroll
    for (int s = 0; s < 8; ++s) v[s] = xs[oct * 8 + s][il];
    rcC[(((size_t)n * NC + c) * IPAD + i0 + il) * 4 + oct] =
        (uint4){bf16pair(v[0], v[1]), bf16pair(v[2], v[3]),
                bf16pair(v[4], v[5]), bf16pair(v[6], v[7])};
}

// ---------------------------------------------------------------------------
// Phase 1b (blocks 1016..1020): MFMA B-frag table from g (2560 uint4).
// Bg[(t*4+j)*64+L] entry s = g[(nn + 128 - (kb+s)) mod H],
//   nn = 16j + (L&15), kb = 32t + (L>>4)*8.
// ---------------------------------------------------------------------------
__device__ void phase1_bg(int bid, int tid, const float* __restrict__ g,
                          uint4* __restrict__ Bg) {
    int idx = (bid - 1016) * 512 + tid;   // 0..2559
    int L  = idx & 63;
    int tj = idx >> 6;                    // t*4 + j
    int nn = (tj & 3) * 16 + (L & 15);
    int kb = (tj >> 2) * 32 + (L >> 4) * 8;
    float bf[8];
#pragma unroll
    for (int s = 0; s < 8; ++s) {
        int d = nn + 128 - (kb + s);
        d += (d < 0) ? H : 0;
        bf[s] = g[d];
    }
    Bg[idx] = (uint4){bf16pair(bf[0], bf[1]), bf16pair(bf[2], bf[3]),
                      bf16pair(bf[4], bf[5]), bf16pair(bf[6], bf[7])};
}

// ---------------------------------------------------------------------------
// Phase 2 (blocks 0..551): banded circulant MFMA GEMM (round-12 verified
// mapping). 2 256-thread units/block; unit = 16 i x 32 y tile, wave w =
// image grp*4+w; 1 A-frag + 2 B-frags + 2 MFMA per kstep, barrier-free
// K-loop. Epilogue: fp16 exchange through LDS, coalesced uint2 stores.
// ---------------------------------------------------------------------------
__device__ void phase2_gemm(int bid, int tid, const uint4* __restrict__ rcC,
                            const uint4* __restrict__ Bg,
                            unsigned short* __restrict__ colp, void* smem) {
    typedef _Float16 LX[16][32][4];
    LX* lx2 = (LX*)smem;               // 2 x 4 KB
    const int unit = tid >> 8;
    const int sub  = tid & 255;
    const int u = bid * 2 + unit;      // 0..1103
    _Float16 (*lx)[32][4] = lx2[unit];

    const int yt  = u % 24;
    const int it  = (u / 24) % 23;
    const int grp = u / (24 * 23);
    const int i0 = it * 16, y0 = yt * 32;
    const int wv = sub >> 6, L = sub & 63;

    const int c0 = (yt + 20) % NC;     // first band chunk
    const uint4* An = rcC + (size_t)(grp * 4 + wv) * NC * IPAD * 4;
    const int arow = i0 + (L & 15);
    const int aoff = L >> 4;

    f32x4 acc0 = (f32x4){0.f, 0.f, 0.f, 0.f};
    f32x4 acc1 = (f32x4){0.f, 0.f, 0.f, 0.f};

    for (int t = 0; t < KSTEPS; ++t) {
        int c = c0 + t;
        c -= (c >= NC) ? NC : 0;
        short8 a = __builtin_bit_cast(short8, An[((size_t)c * IPAD + arow) * 4 + aoff]);
        short8 b0 = __builtin_bit_cast(short8, Bg[(t * 4 + 0) * 64 + L]);
        short8 b1 = __builtin_bit_cast(short8, Bg[(t * 4 + 1) * 64 + L]);
        acc0 = __builtin_amdgcn_mfma_f32_16x16x32_bf16(a, b0, acc0, 0, 0, 0);
        acc1 = __builtin_amdgcn_mfma_f32_16x16x32_bf16(a, b1, acc1, 0, 0, 0);
    }

#pragma unroll
    for (int r = 0; r < 4; ++r) {
        int ilc = (L >> 4) * 4 + r;
        lx[ilc][(L & 15)][wv]      = (_Float16)(acc0[r] * SC);
        lx[ilc][16 + (L & 15)][wv] = (_Float16)(acc1[r] * SC);
    }
    __syncthreads();

    unsigned short* cp = colp + (size_t)grp * W * H * 4;
#pragma unroll
    for (int k2 = 0; k2 < 2; ++k2) {
        int e = sub + k2 * 256;        // 0..511
        int ilc = e >> 5, ylc = e & 31;
        int ig = i0 + ilc;
        if (ig < W) {
            uint2 v = *(const uint2*)&lx[ilc][ylc][0];
            *(uint2*)&cp[((size_t)ig * H + y0 + ylc) * 4] = v;
        }
    }
}

// ---------------------------------------------------------------------------
// Phase 3 (all 1024 blocks): backprojection, 4 images/block (round-10/11
// structure: LDS-pipe bound ~102 us, conflicts 0, FETCH 2.2 MB). In-prologue
// angle constants; zero-conflict 8B-entry LDS; fp16 packed accumulation
// flushed every 16 angles; atomicAdd into zeroed output; XCD swizzle.
// ---------------------------------------------------------------------------
__device__ void phase3_backproj(int bid, int tid,
                                const unsigned short* __restrict__ colp,
                                float* __restrict__ outb, void* smem) {
    H2X2 (*colh)[H] = (H2X2(*)[H])smem;                    // 12288 B
    float2* angs = (float2*)((char*)smem + 12288);         // 720 B

    const int bz  = bid & 7;             // XCD-local under round-robin dispatch
    const int tle = bid >> 3;            // 0..127: 16 u-tiles x 8 v-tiles
    const int g  = bz >> 2;              // image-group
    const int aq = bz & 3;               // angle quarter
    const int a0 = aq * (W / 4);         // 90 angles per block
    const int u0 = (tle >> 3) * 32;
    const int v0 = (tle & 7) * 64;
    const int lane = tid & 63;
    const int tu = tid >> 6;             // 0..7

    const float vf = (float)(v0 + lane - D / 2);
    float uf[4];
#pragma unroll
    for (int r = 0; r < 4; ++r) uf[r] = (float)(u0 + tu + 8 * r - D / 2);

    const h2 hz = {(__fp16)0.f, (__fp16)0.f};
    float acc[4][4];
    h2 haccA[4], haccB[4];
#pragma unroll
    for (int r = 0; r < 4; ++r) {
#pragma unroll
        for (int nn = 0; nn < 4; ++nn) acc[r][nn] = 0.f;
        haccA[r] = hz;
        haccB[r] = hz;
    }

    const uint2* cp = (const uint2*)colp + (size_t)g * W * H;
    const int y1 = tid;                  // 0..511
    const int y2 = tid + 512;            // 512..767 (tid < 256 only)

    if (tid < W / 4) {
        float th = (float)(a0 + tid) * 0.00872664625997164788f;  // pi/360
        float r = SY / 384.0f;
        angs[tid] = make_float2(cosf(th) * r, -sinf(th) * r);
    }
    {
        const int ab = a0 * H;
        colh[0][y1] = __builtin_bit_cast(H2X2, cp[ab + y1]);
        if (tid < 256) colh[0][y2] = __builtin_bit_cast(H2X2, cp[ab + y2]);
    }
    __syncthreads();

    for (int j = 0; j < W / 4; ++j) {
        int a = a0 + j;
        int an = (j + 1 < W / 4) ? (a + 1) : a;
        const int ab = an * H;
        uint2 d = cp[ab + y1];
        uint2 e = make_uint2(0u, 0u);
        if (tid < 256) e = cp[ab + y2];

        const int cb2 = j & 1;
        float2 AB = angs[j];             // LDS broadcast
        float base = fmaf(vf, AB.x, SY);
#pragma unroll
        for (int r = 0; r < 4; ++r) {
            float py = fmaf(uf[r], AB.y, base);
            float wy = __builtin_amdgcn_fractf(py);
            int iy = (int)py;            // trunc == floor (py > 0)
            uint2 lo_raw = *(const uint2*)&colh[cb2][iy];       // ds_read_b64
            uint2 hi_raw = *(const uint2*)&colh[cb2][iy + 1];   // ds_read_b64
            H2X2 lo = __builtin_bit_cast(H2X2, lo_raw);
            H2X2 hi = __builtin_bit_cast(H2X2, hi_raw);
            h2 wy2 = __builtin_amdgcn_cvt_pkrtz(wy, wy);
            haccA[r] += lo.a + wy2 * (hi.a - lo.a);
            haccB[r] += lo.b + wy2 * (hi.b - lo.b);
        }

        if ((j & 15) == 15) {
#pragma unroll
            for (int r = 0; r < 4; ++r) {
                acc[r][0] += (float)haccA[r].x;
                acc[r][1] += (float)haccA[r].y;
                acc[r][2] += (float)haccB[r].x;
                acc[r][3] += (float)haccB[r].y;
                haccA[r] = hz;
                haccB[r] = hz;
            }
        }

        colh[cb2 ^ 1][y1] = __builtin_bit_cast(H2X2, d);
        if (tid < 256) colh[cb2 ^ 1][y2] = __builtin_bit_cast(H2X2, e);
        __syncthreads();
    }

#pragma unroll
    for (int r = 0; r < 4; ++r) {
        acc[r][0] += (float)haccA[r].x;
        acc[r][1] += (float)haccA[r].y;
        acc[r][2] += (float)haccB[r].x;
        acc[r][3] += (float)haccB[r].y;
        int u = u0 + tu + 8 * r;
#pragma unroll
        for (int nn = 0; nn < 4; ++nn) {
            size_t idx = ((size_t)(g * 4 + nn) * D + u) * D + v0 + lane;
            atomicAdd(&outb[idx], acc[r][nn]);
        }
    }
}

// ---------------------------------------------------------------------------
// Cooperative mega-kernel: all phases in one launch, grid.sync() between.
// 1024 blocks x 512 thr = exactly 4 blocks/CU co-resident (<=64 VGPR via
// launch_bounds, 16.6 KB smem). Eliminates ~35 us of inter-launch gaps.
// ---------------------------------------------------------------------------
__global__ __launch_bounds__(512, 8)
void mega_kernel(const float* __restrict__ radon, const float* __restrict__ hG,
                 float* __restrict__ g, uint4* __restrict__ Bg,
                 uint4* __restrict__ rcC, unsigned short* __restrict__ colp,
                 float* __restrict__ out) {
    __shared__ __align__(16) unsigned char smem[SMEM_BYTES];
    cg::grid_group grid = cg::this_grid();
    const int bid = blockIdx.x, tid = threadIdx.x;

    phase0_g_zero(bid, tid, hG, g, (float4*)out, smem);
    __threadfence();
    grid.sync();

    if (bid < 576) phase1_rc(bid, tid, radon, rcC, smem);
    else if (bid >= 1016 && bid < 1021) phase1_bg(bid, tid, g, Bg);
    __threadfence();
    grid.sync();

    if (bid < 552) phase2_gemm(bid, tid, rcC, Bg, colp, smem);
    __threadfence();
    grid.sync();

    phase3_backproj(bid, tid, colp, out, smem);
}

// ---------------------------------------------------------------------------
// Fallback wrappers (used only if cooperative launch is rejected): the same
// phase functions as 4 plain kernels == round-11 structure/performance.
// ---------------------------------------------------------------------------
__global__ __launch_bounds__(512, 8)
void k_p0(const float* __restrict__ hG, float* __restrict__ g, float4* __restrict__ out4) {
    __shared__ __align__(16) unsigned char smem[SMEM_BYTES];
    phase0_g_zero(blockIdx.x, threadIdx.x, hG, g, out4, smem);
}
__global__ __launch_bounds__(512, 8)
void k_p1(const float* __restrict__ radon, const float* __restrict__ g,
          uint4* __restrict__ rcC, uint4* __restrict__ Bg) {
    __shared__ __align__(16) unsigned char smem[SMEM_BYTES];
    int bid = blockIdx.x;
    if (bid < 576) phase1_rc(bid, threadIdx.x, radon, rcC, smem);
    else if (bid >= 1016 && bid < 1021) phase1_bg(bid, threadIdx.x, g, Bg);
}
__global__ __launch_bounds__(512, 8)
void k_p2(const uint4* __restrict__ rcC, const uint4* __restrict__ Bg,
          unsigned short* __restrict__ colp) {
    __shared__ __align__(16) unsigned char smem[SMEM_BYTES];
    phase2_gemm(blockIdx.x, threadIdx.x, rcC, Bg, colp, smem);
}
__global__ __launch_bounds__(512, 8)
void k_p3(const unsigned short* __restrict__ colp, float* __restrict__ out) {
    __shared__ __align__(16) unsigned char smem[SMEM_BYTES];
    phase3_backproj(blockIdx.x, threadIdx.x, colp, out, smem);
}

// ---------------------------------------------------------------------------
// Workspace layout:
//   [0, 3072)              g (768 floats)
//   [8192, 49152)          Bg (2560 uint4 = 40 KB B-frag table)
//   [65536, 4489216)       colp (2 grp x 360 x 768 x 8B fp16-packed columns)
//   [4489216, 9207808)     rcC (8 x 24 x 384 x 64B bf16 A-frag chunks)
// ---------------------------------------------------------------------------
extern "C" void kernel_launch(void* const* d_in, const int* in_sizes, int n_in,
                              void* d_out, int out_size, void* d_ws, size_t ws_size,
                              hipStream_t stream) {
    const float* radon = (const float*)d_in[0];
    const float* hG    = (const float*)d_in[1];
    float* out = (float*)d_out;

    float* g    = (float*)d_ws;
    uint4* Bg   = (uint4*)((char*)d_ws + 8192);
    unsigned short* colp = (unsigned short*)((char*)d_ws + 65536);
    uint4* rcC  = (uint4*)((char*)d_ws + 4489216);

    void* args[] = {(void*)&radon, (void*)&hG, (void*)&g, (void*)&Bg,
                    (void*)&rcC, (void*)&colp, (void*)&out};
    hipError_t err = hipLaunchCooperativeKernel((void*)mega_kernel, dim3(1024),
                                                dim3(512), args, 0, stream);
    if (err != hipSuccess) {
        // Fallback: same phases as 4 plain launches (round-11 equivalent).
        k_p0<<<1024, 512, 0, stream>>>(hG, g, (float4*)out);
        k_p1<<<1024, 512, 0, stream>>>(radon, g, rcC, Bg);
        k_p2<<<552, 512, 0, stream>>>(rcC, Bg, colp);
        k_p3<<<1024, 512, 0, stream>>>(colp, out);
    }
}

// Round 14
// 169.755 us; speedup vs baseline: 5.4523x; 5.4523x over previous
//
#include <hip/hip_runtime.h>
#include <math.h>

// Problem constants (from setup_inputs): N=8, H=768, W=360, D=512
#define N_IMG 8
#define H 768
#define W 360
#define D 512
#define SY 383.5f         // (H-1)/2
#define SC 0.00436332312998582394f  // pi/(2W) = pi/720
#define NC 24             // 768/32 m-chunks
#define IPAD 384          // i dimension padded 360 -> 384
#define KSTEPS 10         // 10 x 32 = K 320 band

typedef __fp16 h2 __attribute__((ext_vector_type(2)));
struct H2X2 { h2 a, b; };        // 8B LDS entry: {img01@y, img23@y}
typedef short short8 __attribute__((ext_vector_type(8)));   // 8 bf16 (4 VGPRs)
typedef float f32x4 __attribute__((ext_vector_type(4)));

// fp32 -> bf16 pair, round-to-nearest-even, packed into one uint
__device__ inline unsigned bf16pair(float a, float b) {
    unsigned ua = __builtin_bit_cast(unsigned, a);
    unsigned ub = __builtin_bit_cast(unsigned, b);
    ua += 0x7FFFu + ((ua >> 16) & 1u);
    ub += 0x7FFFu + ((ub >> 16) & 1u);
    return (ua >> 16) | (ub & 0xFFFF0000u);
}

// ---------------------------------------------------------------------------
// Kernel 1: g[m] = (1/H) sum_k hG[k] cos(2*pi*k*m/H)  (blocks 0..767, 512-thr
// block reduction over 768 k-terms) + zero the atomic output (all 1024
// blocks x 512 thr x 1 float4 = exactly 8 MB).
// ---------------------------------------------------------------------------
__global__ __launch_bounds__(512)
void k_p0(const float* __restrict__ hG, float* __restrict__ g,
          float4* __restrict__ out4) {
    __shared__ float lred[8];
    const int bid = blockIdx.x, tid = threadIdx.x;

    out4[bid * 512 + tid] = make_float4(0.f, 0.f, 0.f, 0.f);
    if (bid < H) {
        int m = bid;
        int p0 = (tid * m) % H;
        float s = hG[tid] * cosf((float)p0 * 0.00818123086872313911f);  // 2pi/768
        if (tid < 256) {
            int k = tid + 512;
            int p1 = (k * m) % H;
            s += hG[k] * cosf((float)p1 * 0.00818123086872313911f);
        }
#pragma unroll
        for (int off = 32; off > 0; off >>= 1) s += __shfl_down(s, off);
        if ((tid & 63) == 0) lred[tid >> 6] = s;
        __syncthreads();
        if (tid == 0) {
            float t = 0.f;
#pragma unroll
            for (int w2 = 0; w2 < 8; ++w2) t += lred[w2];
            g[m] = t * (1.0f / (float)H);
        }
    }
}

// ---------------------------------------------------------------------------
// Kernel 2: blocks 0..575: A-matrix transpose + bf16 pack (px == i exactly ->
// rc[n][i][m] = radon[n][m][i]); 2 256-thread tile-units per block, 1152
// tiles. Blocks 576..580: MFMA B-frag table from g (2560 uint4):
// Bg[(t*4+j)*64+L] entry s = g[(16j+(L&15) + 128 - (32t+(L>>4)*8+s)) mod H].
// ---------------------------------------------------------------------------
__global__ __launch_bounds__(512)
void k_p1(const float* __restrict__ radon, const float* __restrict__ g,
          uint4* __restrict__ rcC, uint4* __restrict__ Bg) {
    __shared__ float xs2[2][32][65];   // 16.6 KB
    const int bid = blockIdx.x, tid = threadIdx.x;

    if (bid < 576) {
        const int unit = tid >> 8;         // 0/1
        const int sub  = tid & 255;
        const int tv = bid * 2 + unit;     // 0..1151
        float (*xs)[65] = xs2[unit];

        const int i0 = (tv % 6) * 64;
        const int c  = (tv / 6) % NC;
        const int n  = tv / 144;

        {
            int mr    = sub >> 3;          // 0..31
            int lane8 = sub & 7;
            int ib = i0 + lane8 * 8;
            const float* src = radon + ((size_t)n * H + 32 * c + mr) * W + ib;
            float4 v0 = make_float4(0.f, 0.f, 0.f, 0.f), v1 = v0;
            if (ib + 7 < W) {              // 360 % 8 == 0: all-valid or all-invalid
                v0 = *(const float4*)src;
                v1 = *(const float4*)(src + 4);
            }
            *(float4*)&xs[mr][lane8 * 8]     = v0;
            *(float4*)&xs[mr][lane8 * 8 + 4] = v1;
        }
        __syncthreads();

        const int il  = sub >> 2;          // 0..63
        const int oct = sub & 3;
        float v[8];
#pragma unroll
        for (int s = 0; s < 8; ++s) v[s] = xs[oct * 8 + s][il];
        rcC[(((size_t)n * NC + c) * IPAD + i0 + il) * 4 + oct] =
            (uint4){bf16pair(v[0], v[1]), bf16pair(v[2], v[3]),
                    bf16pair(v[4], v[5]), bf16pair(v[6], v[7])};
    } else if (bid < 581) {
        int idx = (bid - 576) * 512 + tid;   // 0..2559
        int L  = idx & 63;
        int tj = idx >> 6;                   // t*4 + j
        int nn = (tj & 3) * 16 + (L & 15);
        int kb = (tj >> 2) * 32 + (L >> 4) * 8;
        float bf[8];
#pragma unroll
        for (int s = 0; s < 8; ++s) {
            int d = nn + 128 - (kb + s);
            d += (d < 0) ? H : 0;
            bf[s] = g[d];
        }
        Bg[idx] = (uint4){bf16pair(bf[0], bf[1]), bf16pair(bf[2], bf[3]),
                          bf16pair(bf[4], bf[5]), bf16pair(bf[6], bf[7])};
    }
}

// ---------------------------------------------------------------------------
// Kernel 3: banded circulant MFMA GEMM. 2 256-thread units/block; unit =
// 16 i x 32 y tile, wave w = image grp*4+w; 1 A-frag + 2 B-frags + 2 MFMA
// per kstep, barrier-free K-loop. Epilogue: fp16 exchange through LDS,
// coalesced uint2 stores of {img0..3} pairs. 552 blocks x 512 thr.
// ---------------------------------------------------------------------------
__global__ __launch_bounds__(512)
void k_p2(const uint4* __restrict__ rcC, const uint4* __restrict__ Bg,
          unsigned short* __restrict__ colp) {
    __shared__ _Float16 lx2[2][16][32][4];   // 8 KB
    const int bid = blockIdx.x, tid = threadIdx.x;

    const int unit = tid >> 8;
    const int sub  = tid & 255;
    const int u = bid * 2 + unit;      // 0..1103
    _Float16 (*lx)[32][4] = lx2[unit];

    const int yt  = u % 24;
    const int it  = (u / 24) % 23;
    const int grp = u / (24 * 23);
    const int i0 = it * 16, y0 = yt * 32;
    const int wv = sub >> 6, L = sub & 63;

    const int c0 = (yt + 20) % NC;     // first band chunk: (y0-128)/32 mod 24
    const uint4* An = rcC + (size_t)(grp * 4 + wv) * NC * IPAD * 4;
    const int arow = i0 + (L & 15);
    const int aoff = L >> 4;

    f32x4 acc0 = (f32x4){0.f, 0.f, 0.f, 0.f};
    f32x4 acc1 = (f32x4){0.f, 0.f, 0.f, 0.f};

    for (int t = 0; t < KSTEPS; ++t) {
        int c = c0 + t;
        c -= (c >= NC) ? NC : 0;
        short8 a = __builtin_bit_cast(short8, An[((size_t)c * IPAD + arow) * 4 + aoff]);
        short8 b0 = __builtin_bit_cast(short8, Bg[(t * 4 + 0) * 64 + L]);
        short8 b1 = __builtin_bit_cast(short8, Bg[(t * 4 + 1) * 64 + L]);
        acc0 = __builtin_amdgcn_mfma_f32_16x16x32_bf16(a, b0, acc0, 0, 0, 0);
        acc1 = __builtin_amdgcn_mfma_f32_16x16x32_bf16(a, b1, acc1, 0, 0, 0);
    }

#pragma unroll
    for (int r = 0; r < 4; ++r) {
        int ilc = (L >> 4) * 4 + r;
        lx[ilc][(L & 15)][wv]      = (_Float16)(acc0[r] * SC);
        lx[ilc][16 + (L & 15)][wv] = (_Float16)(acc1[r] * SC);
    }
    __syncthreads();

    unsigned short* cp = colp + (size_t)grp * W * H * 4;
#pragma unroll
    for (int k2 = 0; k2 < 2; ++k2) {
        int e = sub + k2 * 256;        // 0..511
        int ilc = e >> 5, ylc = e & 31;
        int ig = i0 + ilc;
        if (ig < W) {
            uint2 v = *(const uint2*)&lx[ilc][ylc][0];
            *(uint2*)&cp[((size_t)ig * H + y0 + ylc) * 4] = v;
        }
    }
}

// ---------------------------------------------------------------------------
// Kernel 4: backprojection, 4 images/block (proven 101.6 us: LDS-pipe bound,
// conflicts 0, FETCH 2.2 MB). In-prologue angle constants; zero-conflict
// 8B-entry LDS; fp16 packed accumulation flushed every 16 angles; atomicAdd
// into zeroed output; XCD swizzle bz = bid & 7. Grid 1024 x 512 thr.
// ---------------------------------------------------------------------------
__global__ __launch_bounds__(512, 8)
void k_p3(const unsigned short* __restrict__ colp, float* __restrict__ outb) {
    __shared__ __align__(16) H2X2 colh[2][H];   // 12 KB
    __shared__ float2 angs[W / 4];              // 720 B

    const int bid = blockIdx.x;
    const int bz  = bid & 7;             // XCD-local under round-robin dispatch
    const int tle = bid >> 3;            // 0..127: 16 u-tiles x 8 v-tiles
    const int g  = bz >> 2;              // image-group
    const int aq = bz & 3;               // angle quarter
    const int a0 = aq * (W / 4);         // 90 angles per block
    const int u0 = (tle >> 3) * 32;
    const int v0 = (tle & 7) * 64;
    const int tid = threadIdx.x;
    const int lane = tid & 63;
    const int tu = tid >> 6;             // 0..7

    const float vf = (float)(v0 + lane - D / 2);
    float uf[4];
#pragma unroll
    for (int r = 0; r < 4; ++r) uf[r] = (float)(u0 + tu + 8 * r - D / 2);

    const h2 hz = {(__fp16)0.f, (__fp16)0.f};
    float acc[4][4];
    h2 haccA[4], haccB[4];
#pragma unroll
    for (int r = 0; r < 4; ++r) {
#pragma unroll
        for (int nn = 0; nn < 4; ++nn) acc[r][nn] = 0.f;
        haccA[r] = hz;
        haccB[r] = hz;
    }

    const uint2* cp = (const uint2*)colp + (size_t)g * W * H;
    const int y1 = tid;                  // 0..511
    const int y2 = tid + 512;            // 512..767 (tid < 256 only)

    if (tid < W / 4) {
        float th = (float)(a0 + tid) * 0.00872664625997164788f;  // pi/360
        float r = SY / 384.0f;
        angs[tid] = make_float2(cosf(th) * r, -sinf(th) * r);
    }
    {
        const int ab = a0 * H;
        colh[0][y1] = __builtin_bit_cast(H2X2, cp[ab + y1]);
        if (tid < 256) colh[0][y2] = __builtin_bit_cast(H2X2, cp[ab + y2]);
    }
    __syncthreads();

    for (int j = 0; j < W / 4; ++j) {
        int a = a0 + j;
        int an = (j + 1 < W / 4) ? (a + 1) : a;
        const int ab = an * H;
        uint2 d = cp[ab + y1];
        uint2 e = make_uint2(0u, 0u);
        if (tid < 256) e = cp[ab + y2];

        const int cb2 = j & 1;
        float2 AB = angs[j];             // LDS broadcast
        float base = fmaf(vf, AB.x, SY);
#pragma unroll
        for (int r = 0; r < 4; ++r) {
            float py = fmaf(uf[r], AB.y, base);
            float wy = __builtin_amdgcn_fractf(py);
            int iy = (int)py;            // trunc == floor (py > 0)
            uint2 lo_raw = *(const uint2*)&colh[cb2][iy];       // ds_read_b64
            uint2 hi_raw = *(const uint2*)&colh[cb2][iy + 1];   // ds_read_b64
            H2X2 lo = __builtin_bit_cast(H2X2, lo_raw);
            H2X2 hi = __builtin_bit_cast(H2X2, hi_raw);
            h2 wy2 = __builtin_amdgcn_cvt_pkrtz(wy, wy);
            haccA[r] += lo.a + wy2 * (hi.a - lo.a);
            haccB[r] += lo.b + wy2 * (hi.b - lo.b);
        }

        if ((j & 15) == 15) {
#pragma unroll
            for (int r = 0; r < 4; ++r) {
                acc[r][0] += (float)haccA[r].x;
                acc[r][1] += (float)haccA[r].y;
                acc[r][2] += (float)haccB[r].x;
                acc[r][3] += (float)haccB[r].y;
                haccA[r] = hz;
                haccB[r] = hz;
            }
        }

        colh[cb2 ^ 1][y1] = __builtin_bit_cast(H2X2, d);
        if (tid < 256) colh[cb2 ^ 1][y2] = __builtin_bit_cast(H2X2, e);
        __syncthreads();
    }

#pragma unroll
    for (int r = 0; r < 4; ++r) {
        acc[r][0] += (float)haccA[r].x;
        acc[r][1] += (float)haccA[r].y;
        acc[r][2] += (float)haccB[r].x;
        acc[r][3] += (float)haccB[r].y;
        int u = u0 + tu + 8 * r;
#pragma unroll
        for (int nn = 0; nn < 4; ++nn) {
            size_t idx = ((size_t)(g * 4 + nn) * D + u) * D + v0 + lane;
            atomicAdd(&outb[idx], acc[r][nn]);
        }
    }
}

// ---------------------------------------------------------------------------
// Workspace layout:
//   [0, 3072)              g (768 floats)
//   [8192, 49152)          Bg (2560 uint4 = 40 KB B-frag table)
//   [65536, 4489216)       colp (2 grp x 360 x 768 x 8B fp16-packed columns)
//   [4489216, 9207808)     rcC (8 x 24 x 384 x 64B bf16 A-frag chunks)
// ---------------------------------------------------------------------------
extern "C" void kernel_launch(void* const* d_in, const int* in_sizes, int n_in,
                              void* d_out, int out_size, void* d_ws, size_t ws_size,
                              hipStream_t stream) {
    const float* radon = (const float*)d_in[0];
    const float* hG    = (const float*)d_in[1];
    float* out = (float*)d_out;

    float* g    = (float*)d_ws;
    uint4* Bg   = (uint4*)((char*)d_ws + 8192);
    unsigned short* colp = (unsigned short*)((char*)d_ws + 65536);
    uint4* rcC  = (uint4*)((char*)d_ws + 4489216);

    k_p0<<<1024, 512, 0, stream>>>(hG, g, (float4*)out);
    k_p1<<<581, 512, 0, stream>>>(radon, g, rcC, Bg);
    k_p2<<<552, 512, 0, stream>>>(rcC, Bg, colp);
    k_p3<<<1024, 512, 0, stream>>>(colp, out);
}